// Round 1
// baseline (647.447 us; speedup 1.0000x reference)
//
#include <hip/hip_runtime.h>

// Problem: B=128, N=4096, IN=128, OUT=64
//   out[b,n,o] = T * ( LN(x[b,n,:]) @ W_eff + b1[0,n,:] )[o]
//   W_eff[i,o] = sum_g w1[i,o,g]   (g = N axis, contiguous innermost)
// LN refactor: out = rstd*(dot(x, g*W) - mu*Gw) + Bw + b1, all *T
//   Gw[o] = sum_i gamma[i]*W[i,o], Bw[o] = sum_i beta[i]*W[i,o]

constexpr int   Ndim = 4096;
constexpr int   IN   = 128;
constexpr int   OUT  = 64;
constexpr float EPS  = 1e-5f;

// ---------------- Kernel A: reduce w1 over last axis ----------------
// One block per (i,o) pair: sums 4096 contiguous floats.
__global__ __launch_bounds__(256) void reduce_w_kernel(
    const float* __restrict__ w1, float* __restrict__ Weff)
{
    const int p   = blockIdx.x;              // p = i*OUT + o, in [0, 8192)
    const int tid = threadIdx.x;
    const float4* w4 = (const float4*)(w1 + (long)p * Ndim);

    float s = 0.f;
    #pragma unroll
    for (int j = 0; j < 4; ++j) {
        float4 v = w4[j * 256 + tid];        // coalesced
        s += (v.x + v.y) + (v.z + v.w);
    }
    #pragma unroll
    for (int m = 1; m <= 32; m <<= 1) s += __shfl_xor(s, m);

    __shared__ float part[4];
    if ((tid & 63) == 0) part[tid >> 6] = s;
    __syncthreads();
    if (tid == 0) Weff[p] = (part[0] + part[1]) + (part[2] + part[3]);
}

// ---------------- Kernel B: fused LN + matvec + bias + T ----------------
// 256 threads = 4 waves. Each wave processes 8 rows/iter.
// LDS: Wsm (gamma-scaled W_eff, 32KB), xbuf (4 waves x 8 rows x 128, 16KB).
constexpr int ROWS_PER_BLOCK = 256;   // grid = 524288/256 = 2048 blocks

__global__ __launch_bounds__(256) void fused_ln_matvec_kernel(
    const float* __restrict__ x,
    const float* __restrict__ gamma,
    const float* __restrict__ beta,
    const float* __restrict__ Weff,
    const float* __restrict__ b1,
    const float* __restrict__ Tp,
    float* __restrict__ out)
{
    __shared__ float  Wsm[IN * OUT];     // W[i][o], later scaled by gamma[i]
    __shared__ float  Gws[OUT], Bws[OUT];
    __shared__ float  gs[IN], bs[IN];
    __shared__ float4 xbuf[4 * 256];     // [wave][rowInChunk(8)][i4(32)]

    const int tid = threadIdx.x;

    // Stage W_eff into LDS (coalesced float4)
    {
        const float4* W4   = (const float4*)Weff;
        float4*       Wsm4 = (float4*)Wsm;
        #pragma unroll
        for (int k = 0; k < 8; ++k) Wsm4[k * 256 + tid] = W4[k * 256 + tid];
    }
    if (tid < IN) { gs[tid] = gamma[tid]; bs[tid] = beta[tid]; }
    __syncthreads();

    // Gw / Bw from raw W (before gamma-scaling)
    if (tid < OUT) {
        float gw = 0.f, bw = 0.f;
        for (int i = 0; i < IN; ++i) {
            float w = Wsm[i * OUT + tid];
            gw = fmaf(gs[i], w, gw);
            bw = fmaf(bs[i], w, bw);
        }
        Gws[tid] = gw; Bws[tid] = bw;
    }
    __syncthreads();

    // Scale W in place: Wsm[i][o] *= gamma[i]
    #pragma unroll
    for (int k = 0; k < 32; ++k) {
        int e = k * 256 + tid;
        Wsm[e] *= gs[e >> 6];
    }
    __syncthreads();

    const int   lane = tid & 63;
    const int   wave = tid >> 6;
    const float Tv   = Tp[0];
    const float gwr  = Gws[lane];
    const float bwr  = Bws[lane];

    const long row_base = (long)blockIdx.x * ROWS_PER_BLOCK;

    for (int it = 0; it < ROWS_PER_BLOCK / 32; ++it) {
        const long row0 = row_base + it * 32 + wave * 8;

        // ---- Load 8 rows (1024 floats = 256 float4), coalesced ----
        const float4* xr = (const float4*)(x + row0 * IN);
        float4 xv[4];
        #pragma unroll
        for (int k = 0; k < 4; ++k) xv[k] = xr[k * 64 + lane];
        #pragma unroll
        for (int k = 0; k < 4; ++k) xbuf[wave * 256 + k * 64 + lane] = xv[k];

        // ---- Stats: lane's float4 k belongs to row 2k + (lane>=32) ----
        float mu[4], rstd[4];
        #pragma unroll
        for (int k = 0; k < 4; ++k) {
            float s  = (xv[k].x + xv[k].y) + (xv[k].z + xv[k].w);
            float s2 = fmaf(xv[k].x, xv[k].x, fmaf(xv[k].y, xv[k].y,
                       fmaf(xv[k].z, xv[k].z, xv[k].w * xv[k].w)));
            #pragma unroll
            for (int m = 1; m <= 16; m <<= 1) {   // butterfly within 32-lane half
                s  += __shfl_xor(s,  m);
                s2 += __shfl_xor(s2, m);
            }
            float m_   = s * (1.f / IN);
            float var  = fmaf(-m_, m_, s2 * (1.f / IN));
            mu[k]   = m_;
            rstd[k] = rsqrtf(var + EPS);
        }

        __syncthreads();   // xbuf writes visible

        // ---- Matvec: lane = output o; i outer, row inner (W amortized x8) ----
        float acc[8] = {0.f, 0.f, 0.f, 0.f, 0.f, 0.f, 0.f, 0.f};
        #pragma unroll 4
        for (int i4 = 0; i4 < 32; ++i4) {
            const int wb = i4 * 4 * OUT + lane;
            float w0 = Wsm[wb];
            float w1v = Wsm[wb + OUT];
            float w2 = Wsm[wb + 2 * OUT];
            float w3 = Wsm[wb + 3 * OUT];
            #pragma unroll
            for (int r = 0; r < 8; ++r) {
                float4 xq = xbuf[wave * 256 + r * 32 + i4];  // same-addr broadcast
                float a = acc[r];
                a = fmaf(xq.x, w0, a);
                a = fmaf(xq.y, w1v, a);
                a = fmaf(xq.z, w2, a);
                a = fmaf(xq.w, w3, a);
                acc[r] = a;
            }
        }

        // ---- Epilogue ----
        #pragma unroll
        for (int r = 0; r < 8; ++r) {
            float mur = __shfl(mu[r >> 1],   (r & 1) << 5);
            float rsr = __shfl(rstd[r >> 1], (r & 1) << 5);
            long  row = row0 + r;
            int   n   = (int)(row & (Ndim - 1));
            float val = fmaf(acc[r] - mur * gwr, rsr, bwr) + b1[n * OUT + lane];
            out[row * OUT + lane] = val * Tv;
        }

        __syncthreads();   // protect xbuf before next iteration overwrites
    }
}

extern "C" void kernel_launch(void* const* d_in, const int* in_sizes, int n_in,
                              void* d_out, int out_size, void* d_ws, size_t ws_size,
                              hipStream_t stream)
{
    const float* x     = (const float*)d_in[0];
    const float* gamma = (const float*)d_in[1];
    const float* beta  = (const float*)d_in[2];
    const float* w1    = (const float*)d_in[3];
    const float* b1    = (const float*)d_in[4];
    const float* T     = (const float*)d_in[5];
    float*       out   = (float*)d_out;
    float*       Weff  = (float*)d_ws;           // 8192 floats = 32 KB scratch

    // Kernel A: w1 (128,64,4096) -> W_eff (128,64)
    reduce_w_kernel<<<IN * OUT, 256, 0, stream>>>(w1, Weff);

    // Kernel B: fused LayerNorm + matvec + bias + temperature
    const long rows = 128L * 4096L;              // B*N = 524288
    fused_ln_matvec_kernel<<<rows / ROWS_PER_BLOCK, 256, 0, stream>>>(
        x, gamma, beta, Weff, b1, T, out);
}

// Round 2
// 533.691 us; speedup vs baseline: 1.2131x; 1.2131x over previous
//
#include <hip/hip_runtime.h>

// B=128, N=4096, IN=128, OUT=64
// out[b,n,o] = T * ( LN(x[b,n,:]) @ W_eff + b1[0,n,:] )[o],  W_eff[i,o] = sum_g w1[i,o,g]
// LN refactor: out = rstd*(x @ (gamma*W) - mu*Gw) + Bw + b1, all *T
//   Gw[o] = sum_i gamma[i]*W[i,o], Bw[o] = sum_i beta[i]*W[i,o]
// Matvec done with mfma_f32_16x16x32_bf16: M=524288 rows, N(out)=64, K=128.

constexpr int   Ndim = 4096;
constexpr int   IN   = 128;
constexpr int   OUT  = 64;
constexpr float EPS  = 1e-5f;

typedef __bf16 bf16x8 __attribute__((ext_vector_type(8)));
typedef unsigned short ushort8 __attribute__((ext_vector_type(8)));
typedef float f32x4 __attribute__((ext_vector_type(4)));

__device__ __forceinline__ unsigned short f2bf_rne(float f) {
    unsigned int u = __float_as_uint(f);
    u = (u + 0x7FFFu + ((u >> 16) & 1u)) >> 16;   // round-to-nearest-even
    return (unsigned short)u;
}

// ---------------- Kernel A: w1 (128,64,4096) -> Weff (128,64) ----------------
// One wave per (i,o) pair; 16 float4 loads/lane in flight; no LDS, no barrier.
__global__ __launch_bounds__(256) void reduce_w_kernel(
    const float* __restrict__ w1, float* __restrict__ Weff)
{
    const int p    = blockIdx.x * 4 + (threadIdx.x >> 6);   // pair in [0, 8192)
    const int lane = threadIdx.x & 63;
    const float4* w4 = (const float4*)(w1 + (long)p * Ndim);

    float s = 0.f;
    #pragma unroll
    for (int j = 0; j < 16; ++j) {
        float4 v = w4[j * 64 + lane];          // coalesced 1KB/wave per load
        s += (v.x + v.y) + (v.z + v.w);
    }
    #pragma unroll
    for (int m = 1; m <= 32; m <<= 1) s += __shfl_xor(s, m);
    if (lane == 0) Weff[p] = s;
}

// ---------------- Kernel C: prep Gw, Bw, and bf16 B-fragment W ----------------
// Wfrag[kt(4)][nt(4)][lane(64)][j(8)] = bf16( gamma[k] * Weff[k][n] )
//   k = kt*32 + (lane>>4)*8 + j, n = nt*16 + (lane&15)   (MFMA B-operand layout)
__global__ __launch_bounds__(256) void prep_kernel(
    const float* __restrict__ Weff,
    const float* __restrict__ gamma,
    const float* __restrict__ beta,
    float* __restrict__ Gw, float* __restrict__ Bw,
    unsigned short* __restrict__ Wfrag)
{
    const int tid = threadIdx.x;
    __shared__ float Ws[IN * OUT];
    __shared__ float gs[IN], bs[IN];

    #pragma unroll
    for (int k = 0; k < 32; ++k) Ws[k * 256 + tid] = Weff[k * 256 + tid];
    if (tid < IN) { gs[tid] = gamma[tid]; bs[tid] = beta[tid]; }
    __syncthreads();

    if (tid < OUT) {
        float gw = 0.f, bw = 0.f;
        for (int i = 0; i < IN; ++i) {
            float w = Ws[i * OUT + tid];
            gw = fmaf(gs[i], w, gw);
            bw = fmaf(bs[i], w, bw);
        }
        Gw[tid] = gw; Bw[tid] = bw;
    }

    #pragma unroll
    for (int t = 0; t < 32; ++t) {
        int e    = t * 256 + tid;          // [0, 8192)
        int j    = e & 7;
        int lane = (e >> 3) & 63;
        int pr   = e >> 9;                 // kt*4 + nt
        int kt   = pr >> 2, nt = pr & 3;
        int k    = kt * 32 + ((lane >> 4) << 3) + j;
        int n    = nt * 16 + (lane & 15);
        Wfrag[e] = f2bf_rne(gs[k] * Ws[k * OUT + n]);
    }
}

// ---------------- Kernel B: fused LN + MFMA matvec + bias + T ----------------
// 4 waves/block; each wave does 4 chunks of 16 rows. Per chunk:
//   A-frag: lane holds x[row0+(lane&15)][ (lane>>4)*8 + kt*32 .. +8 ]  (fp32->bf16)
//   stats:  lane's 32 x-values union over lanes {L,L^16,L^32,L^48} = full row
//   C-tile: col = lane&15 (-> o = nt*16+col), row = (lane>>4)*4 + reg
constexpr int ROWS_PER_BLOCK = 256;   // grid = 524288/256 = 2048

__global__ __launch_bounds__(256, 3) void fused_mfma_kernel(
    const float* __restrict__ x,
    const unsigned short* __restrict__ Wfrag,
    const float* __restrict__ Gw,
    const float* __restrict__ Bw,
    const float* __restrict__ b1,
    const float* __restrict__ Tp,
    float* __restrict__ out)
{
    const int tid  = threadIdx.x;
    const int wave = tid >> 6;
    const int lane = tid & 63;
    const int q    = lane >> 4;     // quad index
    const int mloc = lane & 15;     // row (A) / col (C) within 16-tile

    // --- B fragments: 16 coalesced dwordx4 loads, held for whole kernel ---
    bf16x8 bfr[4][4];
    const ushort8* wf8 = (const ushort8*)Wfrag;
    #pragma unroll
    for (int kt = 0; kt < 4; ++kt)
        #pragma unroll
        for (int nt = 0; nt < 4; ++nt) {
            ushort8 u = wf8[(kt * 4 + nt) * 64 + lane];
            bfr[kt][nt] = __builtin_bit_cast(bf16x8, u);
        }

    float Gwl[4], Bwl[4];
    #pragma unroll
    for (int nt = 0; nt < 4; ++nt) {
        Gwl[nt] = Gw[nt * 16 + mloc];
        Bwl[nt] = Bw[nt * 16 + mloc];
    }
    const float Tv = Tp[0];

    const long wave_row0 = (long)blockIdx.x * ROWS_PER_BLOCK + wave * 64;

    #pragma unroll
    for (int c = 0; c < 4; ++c) {
        const long row0 = wave_row0 + c * 16;

        // ---- Load 16 rows directly in A-fragment order ----
        const float* xr = x + (row0 + mloc) * IN + q * 8;
        f32x4 xv[8];
        #pragma unroll
        for (int kt = 0; kt < 4; ++kt) {
            xv[2 * kt]     = *(const f32x4*)(xr + kt * 32);
            xv[2 * kt + 1] = *(const f32x4*)(xr + kt * 32 + 4);
        }

        // ---- LN stats (biased var) via 2-step butterfly over row-sharing lanes ----
        float s = 0.f, s2 = 0.f;
        #pragma unroll
        for (int v = 0; v < 8; ++v)
            #pragma unroll
            for (int e = 0; e < 4; ++e) {
                float f = xv[v][e];
                s += f;
                s2 = fmaf(f, f, s2);
            }
        s  += __shfl_xor(s, 16);  s  += __shfl_xor(s, 32);
        s2 += __shfl_xor(s2, 16); s2 += __shfl_xor(s2, 32);
        float mu  = s * (1.f / IN);
        float var = fmaf(-mu, mu, s2 * (1.f / IN));
        float rs  = rsqrtf(var + EPS);

        // ---- Convert to bf16 A-fragments ----
        bf16x8 af[4];
        #pragma unroll
        for (int kt = 0; kt < 4; ++kt) {
            ushort8 t;
            #pragma unroll
            for (int e = 0; e < 4; ++e) {
                t[e]     = f2bf_rne(xv[2 * kt][e]);
                t[e + 4] = f2bf_rne(xv[2 * kt + 1][e]);
            }
            af[kt] = __builtin_bit_cast(bf16x8, t);
        }

        // ---- MFMA: 16 per chunk ----
        f32x4 acc[4] = {{0.f,0.f,0.f,0.f},{0.f,0.f,0.f,0.f},
                        {0.f,0.f,0.f,0.f},{0.f,0.f,0.f,0.f}};
        #pragma unroll
        for (int kt = 0; kt < 4; ++kt)
            #pragma unroll
            for (int nt = 0; nt < 4; ++nt)
                acc[nt] = __builtin_amdgcn_mfma_f32_16x16x32_bf16(
                              af[kt], bfr[kt][nt], acc[nt], 0, 0, 0);

        // ---- Epilogue ----
        #pragma unroll
        for (int r = 0; r < 3 + 1; ++r) {
            int   rloc = q * 4 + r;
            float mur  = __shfl(mu, rloc);
            float rsr  = __shfl(rs, rloc);
            long  row  = row0 + rloc;
            int   n    = (int)(row & (Ndim - 1));
            #pragma unroll
            for (int nt = 0; nt < 4; ++nt) {
                int   o   = nt * 16 + mloc;
                float val = rsr * (acc[nt][r] - mur * Gwl[nt]) + Bwl[nt]
                          + b1[n * OUT + o];
                out[row * OUT + o] = val * Tv;
            }
        }
    }
}

extern "C" void kernel_launch(void* const* d_in, const int* in_sizes, int n_in,
                              void* d_out, int out_size, void* d_ws, size_t ws_size,
                              hipStream_t stream)
{
    const float* x     = (const float*)d_in[0];
    const float* gamma = (const float*)d_in[1];
    const float* beta  = (const float*)d_in[2];
    const float* w1    = (const float*)d_in[3];
    const float* b1    = (const float*)d_in[4];
    const float* T     = (const float*)d_in[5];
    float*       out   = (float*)d_out;

    float*          ws    = (float*)d_ws;
    float*          Weff  = ws;                         // 8192 f
    float*          Gw    = ws + 8192;                  // 64 f
    float*          Bw    = ws + 8192 + 64;             // 64 f
    unsigned short* Wfrag = (unsigned short*)(ws + 8192 + 128);  // 8192 u16

    // A: w1 (128,64,4096) -> Weff (128,64).  8192 pairs / 4 waves = 2048 blocks.
    reduce_w_kernel<<<2048, 256, 0, stream>>>(w1, Weff);

    // C: Gw/Bw + gamma-scaled bf16 W in B-fragment order.
    prep_kernel<<<1, 256, 0, stream>>>(Weff, gamma, beta, Gw, Bw, Wfrag);

    // B: fused LN + MFMA matvec + bias + temperature.
    const long rows = 128L * 4096L;
    fused_mfma_kernel<<<rows / ROWS_PER_BLOCK, 256, 0, stream>>>(
        x, Wfrag, Gw, Bw, b1, T, out);
}